// Round 1
// baseline (173.612 us; speedup 1.0000x reference)
//
#include <hip/hip_runtime.h>
#include <math.h>

#define NODES 4096
#define FIN   512
#define HEADS 4
#define FOUT  128
#define COLS  512   // HEADS*FOUT

// ---------------- Kernel A: feats = X @ Wcat  ([4096,512] x [512,512]) ----------------
// grid (COLS/64, NODES/64), block 256. 64x64 tile, 4x4 per thread, BK=32.
__global__ __launch_bounds__(256) void gemm_feats(
    const float* __restrict__ X, const float* __restrict__ W, float* __restrict__ feats)
{
    const int tid = threadIdx.x;
    const int colBase = blockIdx.x * 64;
    const int rowBase = blockIdx.y * 64;
    const int h     = colBase >> 7;    // 64-col stripe never crosses a 128-col head boundary
    const int obase = colBase & 127;

    __shared__ float As[32][68];   // [kk][m], +4 pad keeps 16B alignment for b128 reads
    __shared__ float Bs[32][64];   // [kk][n]

    const int tx = tid & 15;   // col group
    const int ty = tid >> 4;   // row group

    float acc[4][4];
    #pragma unroll
    for (int i = 0; i < 4; i++)
        #pragma unroll
        for (int j = 0; j < 4; j++) acc[i][j] = 0.f;

    for (int k0 = 0; k0 < FIN; k0 += 32) {
        #pragma unroll
        for (int p = 0; p < 2; p++) {          // stage X tile (transposed into As)
            int v = tid + p * 256;             // v in [0,512)
            int m = v >> 3, kk4 = (v & 7) * 4;
            const float4 x4 = *(const float4*)(X + (size_t)(rowBase + m) * FIN + k0 + kk4);
            As[kk4 + 0][m] = x4.x; As[kk4 + 1][m] = x4.y;
            As[kk4 + 2][m] = x4.z; As[kk4 + 3][m] = x4.w;
        }
        #pragma unroll
        for (int p = 0; p < 2; p++) {          // stage W tile
            int v = tid + p * 256;
            int kk = v >> 4, n4 = (v & 15) * 4;
            int f = k0 + kk;
            const float4 w4 = *(const float4*)(W + ((size_t)(h * FIN + f) * FOUT) + obase + n4);
            *(float4*)&Bs[kk][n4] = w4;
        }
        __syncthreads();
        #pragma unroll
        for (int kk = 0; kk < 32; kk++) {
            float4 a4 = *(const float4*)&As[kk][ty * 4];
            float4 b4 = *(const float4*)&Bs[kk][tx * 4];
            float av[4] = {a4.x, a4.y, a4.z, a4.w};
            float bv[4] = {b4.x, b4.y, b4.z, b4.w};
            #pragma unroll
            for (int i = 0; i < 4; i++)
                #pragma unroll
                for (int j = 0; j < 4; j++)
                    acc[i][j] = fmaf(av[i], bv[j], acc[i][j]);
        }
        __syncthreads();
    }
    #pragma unroll
    for (int i = 0; i < 4; i++) {
        int r = rowBase + ty * 4 + i;
        *(float4*)(feats + (size_t)r * COLS + colBase + tx * 4) =
            make_float4(acc[i][0], acc[i][1], acc[i][2], acc[i][3]);
    }
}

// ---------------- Kernel B: e_s[h,n], e_n[h,n] ----------------
// grid NODES, block 64 (one wave per node)
__global__ __launch_bounds__(64) void scores(
    const float* __restrict__ feats, const float* __restrict__ a_self,
    const float* __restrict__ a_neigh, float* __restrict__ e_s, float* __restrict__ e_n)
{
    const int n = blockIdx.x;
    const int l = threadIdx.x;   // 0..63
    float ps[HEADS], pn[HEADS];
    #pragma unroll
    for (int hh = 0; hh < HEADS; hh++) {
        float x0 = feats[(size_t)n * COLS + hh * FOUT + l];
        float x1 = feats[(size_t)n * COLS + hh * FOUT + l + 64];
        ps[hh] = x0 * a_self[hh * FOUT + l]  + x1 * a_self[hh * FOUT + l + 64];
        pn[hh] = x0 * a_neigh[hh * FOUT + l] + x1 * a_neigh[hh * FOUT + l + 64];
    }
    #pragma unroll
    for (int off = 32; off > 0; off >>= 1) {
        #pragma unroll
        for (int hh = 0; hh < HEADS; hh++) {
            ps[hh] += __shfl_xor(ps[hh], off, 64);
            pn[hh] += __shfl_xor(pn[hh], off, 64);
        }
    }
    if (l == 0) {
        #pragma unroll
        for (int hh = 0; hh < HEADS; hh++) {
            e_s[hh * NODES + n] = ps[hh];
            e_n[hh * NODES + n] = pn[hh];
        }
    }
}

// ---------------- Kernel C: sparse softmax + aggregate + bias + relu ----------------
// grid NODES (one block per destination row), block 256
__global__ __launch_bounds__(256) void aggregate(
    const float* __restrict__ A, const float* __restrict__ feats,
    const float* __restrict__ e_s, const float* __restrict__ e_n,
    const float* __restrict__ bias, float* __restrict__ out)
{
    const int i = blockIdx.x;
    const int tid = threadIdx.x;
    __shared__ int   s_idx[NODES];        // worst case: all neighbors
    __shared__ int   s_cnt;
    __shared__ float s_m[HEADS], s_d[HEADS];
    if (tid == 0) s_cnt = 0;
    __syncthreads();

    // Phase 1: compact neighbor list (exp of masked logits underflows to exactly 0,
    // so the softmax is exactly sparse over A[i,j]==1)
    const float4* Arow = (const float4*)(A + (size_t)i * NODES);
    for (int q = tid; q < NODES / 4; q += 256) {
        float4 a = Arow[q];
        int j = q * 4;
        if (a.x != 0.f) { int p = atomicAdd(&s_cnt, 1); s_idx[p] = j; }
        if (a.y != 0.f) { int p = atomicAdd(&s_cnt, 1); s_idx[p] = j + 1; }
        if (a.z != 0.f) { int p = atomicAdd(&s_cnt, 1); s_idx[p] = j + 2; }
        if (a.w != 0.f) { int p = atomicAdd(&s_cnt, 1); s_idx[p] = j + 3; }
    }
    __syncthreads();
    const int cnt = s_cnt;

    // Phase 2a: per-head max & denom (wave w handles head w)
    {
        const int wv = tid >> 6;
        const int lane = tid & 63;
        const float esi = e_s[wv * NODES + i];
        float m = -1e30f;
        for (int k = lane; k < cnt; k += 64) {
            int j = s_idx[k];
            float e = esi + e_n[wv * NODES + j];
            float l = e > 0.f ? e : 0.2f * e;
            m = fmaxf(m, l);
        }
        #pragma unroll
        for (int off = 32; off > 0; off >>= 1) m = fmaxf(m, __shfl_xor(m, off, 64));
        float d = 0.f;
        for (int k = lane; k < cnt; k += 64) {
            int j = s_idx[k];
            float e = esi + e_n[wv * NODES + j];
            float l = e > 0.f ? e : 0.2f * e;
            d += __expf(l - m);
        }
        #pragma unroll
        for (int off = 32; off > 0; off >>= 1) d += __shfl_xor(d, off, 64);
        if (lane == 0) { s_m[wv] = m; s_d[wv] = d; }
    }
    __syncthreads();

    // Phase 2b: each thread owns columns tid and tid+256
    const int c0 = tid, c1 = tid + 256;
    const int h0 = c0 >> 7, h1 = c1 >> 7;
    const float es0 = e_s[h0 * NODES + i], es1 = e_s[h1 * NODES + i];
    const float m0 = s_m[h0], m1 = s_m[h1];
    float acc0 = 0.f, acc1 = 0.f;
    for (int k = 0; k < cnt; k++) {
        int j = s_idx[k];
        float en0 = e_n[h0 * NODES + j], en1 = e_n[h1 * NODES + j];
        float l0 = es0 + en0; l0 = l0 > 0.f ? l0 : 0.2f * l0;
        float l1 = es1 + en1; l1 = l1 > 0.f ? l1 : 0.2f * l1;
        float w0 = __expf(l0 - m0), w1 = __expf(l1 - m1);
        acc0 = fmaf(w0, feats[(size_t)j * COLS + c0], acc0);
        acc1 = fmaf(w1, feats[(size_t)j * COLS + c1], acc1);
    }
    float o0 = acc0 / s_d[h0] + bias[h0 * FOUT + (c0 & 127)];
    float o1 = acc1 / s_d[h1] + bias[h1 * FOUT + (c1 & 127)];
    out[(size_t)i * COLS + c0] = o0 > 0.f ? o0 : 0.f;
    out[(size_t)i * COLS + c1] = o1 > 0.f ? o1 : 0.f;
}

extern "C" void kernel_launch(void* const* d_in, const int* in_sizes, int n_in,
                              void* d_out, int out_size, void* d_ws, size_t ws_size,
                              hipStream_t stream) {
    const float* X       = (const float*)d_in[0];
    const float* A       = (const float*)d_in[1];
    const float* W       = (const float*)d_in[2];
    const float* b       = (const float*)d_in[3];
    const float* a_self  = (const float*)d_in[4];
    const float* a_neigh = (const float*)d_in[5];
    float* out = (float*)d_out;

    float* feats = (float*)d_ws;                     // [NODES, COLS]  8 MB
    float* e_s   = feats + (size_t)NODES * COLS;     // [HEADS, NODES] 64 KB
    float* e_n   = e_s + HEADS * NODES;              // [HEADS, NODES] 64 KB

    dim3 gA(COLS / 64, NODES / 64);
    gemm_feats<<<gA, 256, 0, stream>>>(X, W, feats);
    scores<<<NODES, 64, 0, stream>>>(feats, a_self, a_neigh, e_s, e_n);
    aggregate<<<NODES, 256, 0, stream>>>(A, feats, e_s, e_n, b, out);
}

// Round 2
// 162.368 us; speedup vs baseline: 1.0693x; 1.0693x over previous
//
#include <hip/hip_runtime.h>
#include <math.h>

#define NODES 4096
#define FIN   512
#define HEADS 4
#define FOUT  128
#define COLS  512   // HEADS*FOUT

typedef short  short8  __attribute__((ext_vector_type(8)));
typedef float  floatx4 __attribute__((ext_vector_type(4)));

// ---------------- Kernel 0: split X and W into (hi, lo) bf16 pairs ----------------
// Xhi/Xlo: [NODES][FIN] bf16. Wthi/Wtlo: [COLS][FIN] bf16, Wt[n][f] = W[h][f][o], n=h*128+o.
__device__ inline void split2(float x, short& hi, short& lo) {
    unsigned xb = __float_as_uint(x);
    unsigned hb = xb & 0xFFFF0000u;
    float hf = __uint_as_float(hb);
    float r  = x - hf;
    hi = (short)(hb >> 16);
    lo = (short)(__float_as_uint(r) >> 16);
}

__global__ __launch_bounds__(256) void convert_split(
    const float* __restrict__ X, const float* __restrict__ W,
    short* __restrict__ Xhi, short* __restrict__ Xlo,
    short* __restrict__ Wthi, short* __restrict__ Wtlo)
{
    int t = blockIdx.x * 256 + threadIdx.x;
    const int NX = NODES * FIN;          // 2,097,152
    const int stride = gridDim.x * 256;
    for (int i = t; i < NX; i += stride) {
        short hi, lo; split2(X[i], hi, lo);
        Xhi[i] = hi; Xlo[i] = lo;
    }
    const int NW = HEADS * FIN * FOUT;   // 262,144
    for (int i = t; i < NW; i += stride) {
        int h = i >> 16;                 // FIN*FOUT = 65536
        int f = (i >> 7) & (FIN - 1);
        int o = i & (FOUT - 1);
        short hi, lo; split2(W[i], hi, lo);
        size_t dst = (size_t)(h * FOUT + o) * FIN + f;
        Wthi[dst] = hi; Wtlo[dst] = lo;
    }
}

// ---------------- Kernel A: feats = X @ Wcat via split-bf16 MFMA ----------------
// grid (COLS/64, NODES/64) = (8,64) = 512 blocks, 256 threads (4 waves).
// Each block: 64x64 C tile; wave w owns 16-col stripe. BK=32, 16 K-iters.
// acc = xh*wh + xh*wl + xl*wh  (lo*lo term ~2^-16 rel, dropped)
__global__ __launch_bounds__(256) void gemm_mfma(
    const short* __restrict__ Xhi, const short* __restrict__ Xlo,
    const short* __restrict__ Bthi, const short* __restrict__ Btlo,
    float* __restrict__ feats)
{
    __shared__ short Ah[64][40], Al[64][40], Bh[64][40], Bl[64][40]; // stride 40 breaks bank aliasing
    const int tid = threadIdx.x;
    const int rowBase = blockIdx.y * 64;
    const int colBase = blockIdx.x * 64;
    const int lane = tid & 63, w = tid >> 6;
    const int quad = lane >> 4, lk = quad * 8, lm = lane & 15;

    floatx4 acc[4];
    #pragma unroll
    for (int mi = 0; mi < 4; mi++) acc[mi] = (floatx4)0.f;

    const int sr = tid >> 2;        // staging row 0..63
    const int sk = (tid & 3) * 8;   // staging k offset

    for (int k0 = 0; k0 < FIN; k0 += 32) {
        const float4 ah = *(const float4*)(Xhi  + (size_t)(rowBase + sr) * FIN + k0 + sk);
        const float4 al = *(const float4*)(Xlo  + (size_t)(rowBase + sr) * FIN + k0 + sk);
        const float4 bh = *(const float4*)(Bthi + (size_t)(colBase + sr) * FIN + k0 + sk);
        const float4 bl = *(const float4*)(Btlo + (size_t)(colBase + sr) * FIN + k0 + sk);
        __syncthreads();
        *(float4*)&Ah[sr][sk] = ah;
        *(float4*)&Al[sr][sk] = al;
        *(float4*)&Bh[sr][sk] = bh;
        *(float4*)&Bl[sr][sk] = bl;
        __syncthreads();

        short8 afh[4], afl[4];
        #pragma unroll
        for (int mi = 0; mi < 4; mi++) {
            afh[mi] = *(const short8*)&Ah[mi * 16 + lm][lk];
            afl[mi] = *(const short8*)&Al[mi * 16 + lm][lk];
        }
        short8 bfh = *(const short8*)&Bh[w * 16 + lm][lk];
        short8 bfl = *(const short8*)&Bl[w * 16 + lm][lk];
        #pragma unroll
        for (int mi = 0; mi < 4; mi++) {
            acc[mi] = __builtin_amdgcn_mfma_f32_16x16x32_bf16(afh[mi], bfh, acc[mi], 0, 0, 0);
            acc[mi] = __builtin_amdgcn_mfma_f32_16x16x32_bf16(afh[mi], bfl, acc[mi], 0, 0, 0);
            acc[mi] = __builtin_amdgcn_mfma_f32_16x16x32_bf16(afl[mi], bfh, acc[mi], 0, 0, 0);
        }
    }
    // C/D layout: col = lane&15, row = quad*4 + reg  [verified m89/m91]
    #pragma unroll
    for (int mi = 0; mi < 4; mi++) {
        #pragma unroll
        for (int r = 0; r < 4; r++) {
            int row = rowBase + mi * 16 + quad * 4 + r;
            int col = colBase + w * 16 + lm;
            feats[(size_t)row * COLS + col] = acc[mi][r];
        }
    }
}

// ---------------- Kernel B: e_s[h,n], e_n[h,n] ----------------
__global__ __launch_bounds__(64) void scores(
    const float* __restrict__ feats, const float* __restrict__ a_self,
    const float* __restrict__ a_neigh, float* __restrict__ e_s, float* __restrict__ e_n)
{
    const int n = blockIdx.x;
    const int l = threadIdx.x;
    float ps[HEADS], pn[HEADS];
    #pragma unroll
    for (int hh = 0; hh < HEADS; hh++) {
        float x0 = feats[(size_t)n * COLS + hh * FOUT + l];
        float x1 = feats[(size_t)n * COLS + hh * FOUT + l + 64];
        ps[hh] = x0 * a_self[hh * FOUT + l]  + x1 * a_self[hh * FOUT + l + 64];
        pn[hh] = x0 * a_neigh[hh * FOUT + l] + x1 * a_neigh[hh * FOUT + l + 64];
    }
    #pragma unroll
    for (int off = 32; off > 0; off >>= 1) {
        #pragma unroll
        for (int hh = 0; hh < HEADS; hh++) {
            ps[hh] += __shfl_xor(ps[hh], off, 64);
            pn[hh] += __shfl_xor(pn[hh], off, 64);
        }
    }
    if (l == 0) {
        #pragma unroll
        for (int hh = 0; hh < HEADS; hh++) {
            e_s[hh * NODES + n] = ps[hh];
            e_n[hh * NODES + n] = pn[hh];
        }
    }
}

// ---------------- Kernel C: sparse softmax + aggregate + bias + relu ----------------
// One block per destination row. Weights computed ONCE per (head, neighbor) by
// wave h, cached in LDS; accumulate loop is pure fmaf + broadcast LDS reads.
__global__ __launch_bounds__(256) void aggregate(
    const float* __restrict__ A, const float* __restrict__ feats,
    const float* __restrict__ e_s, const float* __restrict__ e_n,
    const float* __restrict__ bias, float* __restrict__ out)
{
    const int i = blockIdx.x;
    const int tid = threadIdx.x;
    __shared__ int   s_idx[NODES];          // 16 KB
    __shared__ float s_w[HEADS][512];       // 8 KB, chunked weights
    __shared__ int   s_cnt;
    __shared__ float s_dinv[HEADS];
    if (tid == 0) s_cnt = 0;
    __syncthreads();

    // Phase 1: compact neighbor list (masked-out exp underflows to exactly 0)
    const float4* Arow = (const float4*)(A + (size_t)i * NODES);
    for (int q = tid; q < NODES / 4; q += 256) {
        float4 a = Arow[q];
        int j = q * 4;
        if (a.x != 0.f) s_idx[atomicAdd(&s_cnt, 1)] = j;
        if (a.y != 0.f) s_idx[atomicAdd(&s_cnt, 1)] = j + 1;
        if (a.z != 0.f) s_idx[atomicAdd(&s_cnt, 1)] = j + 2;
        if (a.w != 0.f) s_idx[atomicAdd(&s_cnt, 1)] = j + 3;
    }
    __syncthreads();
    const int cnt = s_cnt;

    const int wv = tid >> 6, lane = tid & 63;   // wave wv owns head wv
    const float esi = e_s[wv * NODES + i];

    // Phase 2a: per-head max
    float m = -1e30f;
    for (int k = lane; k < cnt; k += 64) {
        float e = esi + e_n[wv * NODES + s_idx[k]];
        m = fmaxf(m, e > 0.f ? e : 0.2f * e);
    }
    #pragma unroll
    for (int off = 32; off > 0; off >>= 1) m = fmaxf(m, __shfl_xor(m, off, 64));

    // Phase 2b: chunked weight computation + column accumulation
    const int c0 = tid, c1 = tid + 256;
    const int h0 = c0 >> 7, h1 = c1 >> 7;       // wave-uniform
    float acc0 = 0.f, acc1 = 0.f, d = 0.f;
    for (int base = 0; base < cnt; base += 512) {
        int nc = min(512, cnt - base);
        __syncthreads();
        for (int k = lane; k < nc; k += 64) {
            float e = esi + e_n[wv * NODES + s_idx[base + k]];
            float l = e > 0.f ? e : 0.2f * e;
            float wgt = __expf(l - m);
            s_w[wv][k] = wgt;
            d += wgt;
        }
        __syncthreads();
        for (int k = 0; k < nc; k++) {
            size_t off = (size_t)s_idx[base + k] * COLS;
            acc0 = fmaf(s_w[h0][k], feats[off + c0], acc0);
            acc1 = fmaf(s_w[h1][k], feats[off + c1], acc1);
        }
    }
    #pragma unroll
    for (int off = 32; off > 0; off >>= 1) d += __shfl_xor(d, off, 64);
    if (lane == 0) s_dinv[wv] = 1.f / d;
    __syncthreads();

    float o0 = acc0 * s_dinv[h0] + bias[h0 * FOUT + (c0 & 127)];
    float o1 = acc1 * s_dinv[h1] + bias[h1 * FOUT + (c1 & 127)];
    out[(size_t)i * COLS + c0] = fmaxf(o0, 0.f);
    out[(size_t)i * COLS + c1] = fmaxf(o1, 0.f);
}

extern "C" void kernel_launch(void* const* d_in, const int* in_sizes, int n_in,
                              void* d_out, int out_size, void* d_ws, size_t ws_size,
                              hipStream_t stream) {
    const float* X       = (const float*)d_in[0];
    const float* A       = (const float*)d_in[1];
    const float* W       = (const float*)d_in[2];
    const float* b       = (const float*)d_in[3];
    const float* a_self  = (const float*)d_in[4];
    const float* a_neigh = (const float*)d_in[5];
    float* out = (float*)d_out;

    // Workspace layout
    float* feats = (float*)d_ws;                          // 8 MB
    float* e_s   = feats + (size_t)NODES * COLS;          // 64 KB
    float* e_n   = e_s + HEADS * NODES;                   // 64 KB
    short* Xhi   = (short*)(e_n + HEADS * NODES);         // 4 MB
    short* Xlo   = Xhi + (size_t)NODES * FIN;             // 4 MB
    short* Wthi  = Xlo + (size_t)NODES * FIN;             // 512 KB
    short* Wtlo  = Wthi + (size_t)COLS * FIN;             // 512 KB

    convert_split<<<2048, 256, 0, stream>>>(X, W, Xhi, Xlo, Wthi, Wtlo);
    dim3 gA(COLS / 64, NODES / 64);
    gemm_mfma<<<gA, 256, 0, stream>>>(Xhi, Xlo, Wthi, Wtlo, feats);
    scores<<<NODES, 64, 0, stream>>>(feats, a_self, a_neigh, e_s, e_n);
    aggregate<<<NODES, 256, 0, stream>>>(A, feats, e_s, e_n, b, out);
}